// Round 1
// baseline (398.073 us; speedup 1.0000x reference)
//
#include <hip/hip_runtime.h>
#include <math.h>

#define BB 2
#define LSEQ 2048
#define H 32
#define PDIM 64
#define NDIM 128
#define CS 256
#define NC 8

// ---------------- ws layout (bytes) ----------------
// dtf    : f32 [BB][NC][H][CS]      @ 0        (512 KB)
// cum    : f32 [BB][NC][H][CS]      @ 524288   (512 KB)
// cdecay : f32 [BB][NC][H]          @ 1048576  (2 KB)
// CBf    : f32 [BB][NC][CS][CS]     @ 1052672  (4 MB)   (s-major, l fastest)
// states : f32 [BB][NC][H][NDIM][PDIM] @ 5246976 (16 MB)

__device__ __forceinline__ int dot4i8(int a, int b, int c) {
#if __has_builtin(__builtin_amdgcn_sdot4)
    return __builtin_amdgcn_sdot4(a, b, c, false);
#else
    c += ((a << 24) >> 24) * ((b << 24) >> 24);
    c += ((a << 16) >> 24) * ((b << 16) >> 24);
    c += ((a << 8) >> 24) * ((b << 8) >> 24);
    c += (a >> 24) * (b >> 24);
    return c;
#endif
}

// K1: dtf = softplus(dt*scale+bias); cum = cumsum(dtf*A) within chunk; cdecay = exp(cum[-1])
__global__ __launch_bounds__(256) void k1_dtcum(
    const int* __restrict__ dt, const int* __restrict__ qA,
    const float* __restrict__ dt_bias,
    const float* __restrict__ A_scale_p, const float* __restrict__ dt_scale_p,
    float* __restrict__ dtf, float* __restrict__ cum, float* __restrict__ cdecay)
{
    int t = threadIdx.x;
    int h = blockIdx.x & 31;
    int z = (blockIdx.x >> 5) & 7;
    int b = blockIdx.x >> 8;
    int l = z * CS + t;
    float dt_scale = *dt_scale_p;
    float A = -__expf((float)qA[h] * (*A_scale_p));
    float raw = (float)dt[(b * LSEQ + l) * H + h];
    float xin = raw * dt_scale + dt_bias[h];
    float sp = (xin > 20.f) ? xin : log1pf(__expf(xin));
    float dA = sp * A;

    __shared__ float arr[CS];
    arr[t] = dA;
    __syncthreads();
    for (int off = 1; off < CS; off <<= 1) {
        float v = (t >= off) ? arr[t - off] : 0.f;
        __syncthreads();
        arr[t] += v;
        __syncthreads();
    }
    int base = ((b * NC + z) * H + h) * CS;
    dtf[base + t] = sp;
    cum[base + t] = arr[t];
    if (t == CS - 1) cdecay[(b * NC + z) * H + h] = __expf(arr[t]);
}

// K2: CBf[b][z][s][l] = (C[l] . B[s]) * B_scale*C_scale   (head-independent, G=1)
__global__ __launch_bounds__(256) void k2_cb(
    const int* __restrict__ Bm, const int* __restrict__ Cm,
    const float* __restrict__ Bs_p, const float* __restrict__ Cs_p,
    float* __restrict__ CBf)
{
    __shared__ int Bi[64][33];   // packed 4x i8, +1 pad
    __shared__ int Ci[64][33];
    int t = threadIdx.x;
    int lt = blockIdx.x & 3, st = (blockIdx.x >> 2) & 3;
    int z = (blockIdx.x >> 4) & 7, b = blockIdx.x >> 7;
    int l0 = lt * 64, s0 = st * 64;
    const int* Bp = Bm + (size_t)(b * LSEQ + z * CS + s0) * NDIM;
    const int* Cp = Cm + (size_t)(b * LSEQ + z * CS + l0) * NDIM;
    for (int i = t; i < 64 * 32; i += 256) {
        int r = i >> 5, k = i & 31;
        const int* sb = Bp + r * NDIM + k * 4;
        const int* sc = Cp + r * NDIM + k * 4;
        Bi[r][k] = (sb[0] & 255) | ((sb[1] & 255) << 8) | ((sb[2] & 255) << 16) | ((sb[3] & 255) << 24);
        Ci[r][k] = (sc[0] & 255) | ((sc[1] & 255) << 8) | ((sc[2] & 255) << 16) | ((sc[3] & 255) << 24);
    }
    __syncthreads();
    float cbscale = (*Bs_p) * (*Cs_p);
    int ss = t & 63, lg = t >> 6;   // lg is wave-uniform
    int acc[16];
#pragma unroll
    for (int i = 0; i < 16; ++i) acc[i] = 0;
    for (int k = 0; k < 32; ++k) {
        int bw = Bi[ss][k];
#pragma unroll
        for (int li = 0; li < 16; ++li)
            acc[li] = dot4i8(bw, Ci[lg * 16 + li][k], acc[li]);
    }
    float* outp = CBf + ((size_t)((b * NC + z) * CS + s0 + ss)) * CS + l0 + lg * 16;
#pragma unroll
    for (int li = 0; li < 16; ++li) outp[li] = (float)acc[li] * cbscale;
}

// K3: states[b][z][h][n][p] = sum_s B[s,n]*dtf[s]*exp(cum[255]-cum[s]) * x[s,p] * x_scale*B_scale
__global__ __launch_bounds__(256) void k3_states(
    const int* __restrict__ xq, const int* __restrict__ Bm,
    const float* __restrict__ xs_p, const float* __restrict__ Bs_p,
    const float* __restrict__ dtf, const float* __restrict__ cum,
    float* __restrict__ states)
{
    __shared__ float Bt[64][128];
    __shared__ float xt[64][64];
    __shared__ float coeff[64];
    int t = threadIdx.x;
    int h = blockIdx.x & 31, z = (blockIdx.x >> 5) & 7, b = blockIdx.x >> 8;
    int base = ((b * NC + z) * H + h) * CS;
    float cumlast = cum[base + CS - 1];
    float sc = (*xs_p) * (*Bs_p);
    int n = t >> 1, p0 = (t & 1) * 32;
    float acc[32];
#pragma unroll
    for (int j = 0; j < 32; ++j) acc[j] = 0.f;

    for (int tile = 0; tile < 4; ++tile) {
        int s0 = tile * 64;
        __syncthreads();
        if (t < 64)
            coeff[t] = dtf[base + s0 + t] * __expf(cumlast - cum[base + s0 + t]) * sc;
        for (int i = t; i < 64 * 128; i += 256) {
            int s = i >> 7, nn = i & 127;
            Bt[s][nn] = (float)Bm[(size_t)(b * LSEQ + z * CS + s0 + s) * NDIM + nn];
        }
        for (int i = t; i < 64 * 64; i += 256) {
            int s = i >> 6, pp = i & 63;
            xt[s][pp] = (float)xq[((size_t)(b * LSEQ + z * CS + s0 + s) * H + h) * PDIM + pp];
        }
        __syncthreads();
        for (int s = 0; s < 64; ++s) {
            float bv = Bt[s][n] * coeff[s];
#pragma unroll
            for (int j = 0; j < 32; ++j) acc[j] += bv * xt[s][p0 + j];
        }
    }
    float* op = states + (((size_t)(b * NC + z) * H + h) * NDIM + n) * PDIM + p0;
#pragma unroll
    for (int j = 0; j < 32; ++j) op[j] = acc[j];
}

// K4: in-place inter-chunk scan: states[z] <- state entering chunk z
__global__ __launch_bounds__(256) void k4_scan(
    const float* __restrict__ cdecay, float* __restrict__ states)
{
    int idx = blockIdx.x * 256 + threadIdx.x;   // (b,h,n,p), p fastest
    int p = idx & 63, n = (idx >> 6) & 127, h = (idx >> 13) & 31, b = idx >> 18;
    float carry = 0.f;
    for (int z = 0; z < NC; ++z) {
        size_t off = (((size_t)(b * NC + z) * H + h) * NDIM + n) * PDIM + p;
        float v = states[off];
        float d = cdecay[(b * NC + z) * H + h];
        states[off] = carry;
        carry = d * carry + v;
    }
}

// K5: y_intra[l,p] = sum_{s<=l} CB[s][l]*exp(cum[l]-cum[s])*dtf[s]*x_scale * x[s,p]
__global__ __launch_bounds__(256) void k5_intra(
    const int* __restrict__ xq, const float* __restrict__ CBf,
    const float* __restrict__ dtf, const float* __restrict__ cum,
    const float* __restrict__ xs_p,
    float* __restrict__ out)
{
    __shared__ float xf[256][32];
    __shared__ float cumL[CS];
    __shared__ float dtx[CS];
    int t = threadIdx.x;
    int h = blockIdx.x & 31, z = (blockIdx.x >> 5) & 7, b = blockIdx.x >> 8;
    int base = ((b * NC + z) * H + h) * CS;
    float xs = *xs_p;
    cumL[t] = cum[base + t];
    dtx[t] = dtf[base + t] * xs;
    const float* cbp = CBf + (size_t)((b * NC + z) * CS) * CS + t;
    int smax = t | 63;                 // wave-uniform early exit
    for (int ph = 0; ph < 2; ++ph) {
        __syncthreads();
        for (int i = t; i < 256 * 32; i += 256) {
            int s = i >> 5, j = i & 31;
            xf[s][j] = (float)xq[((size_t)(b * LSEQ + z * CS + s) * H + h) * PDIM + ph * 32 + j];
        }
        __syncthreads();
        float mycum = cumL[t];
        float acc[32];
#pragma unroll
        for (int j = 0; j < 32; ++j) acc[j] = 0.f;
        for (int s = 0; s <= smax; ++s) {
            float cb = cbp[(size_t)s * CS];
            float e = __expf(mycum - cumL[s]);
            float w = (s <= t) ? cb * e * dtx[s] : 0.f;
#pragma unroll
            for (int j = 0; j < 32; ++j) acc[j] += w * xf[s][j];
        }
        float* op = out + ((size_t)(b * LSEQ + z * CS + t) * H + h) * PDIM + ph * 32;
#pragma unroll
        for (int j = 0; j < 32; ++j) op[j] = acc[j];
    }
}

// K6: out += exp(cum[l])*C_scale * (C[l] . prev[p,:]) + x*x_scale*D
__global__ __launch_bounds__(256) void k6_inter(
    const int* __restrict__ xq, const int* __restrict__ Cm,
    const int* __restrict__ qD,
    const float* __restrict__ cum, const float* __restrict__ prevs,
    const float* __restrict__ Cs_p, const float* __restrict__ xs_p, const float* __restrict__ Ds_p,
    float* __restrict__ out)
{
    __shared__ float prevT[128][64];       // [n][p]
    __shared__ signed char Ci[128][132];   // pitch 132 -> conflict-free
    int t = threadIdx.x;
    int h = blockIdx.x & 31, z = (blockIdx.x >> 5) & 7, b = blockIdx.x >> 8;
    int base = ((b * NC + z) * H + h) * CS;
    const float* pp = prevs + ((size_t)(b * NC + z) * H + h) * NDIM * PDIM;
    for (int i = t; i < 128 * 64; i += 256) ((float*)prevT)[i] = pp[i];

    int lrow = t & 31, pg = t >> 5;
    int p0 = pg * 8;
    float Csc = *Cs_p, xs = *xs_p;
    float Df = (float)qD[h] * (*Ds_p);

    for (int lhalf = 0; lhalf < 2; ++lhalf) {
        __syncthreads();
        for (int i = t; i < 128 * 128; i += 256) {
            int r = i >> 7, nn = i & 127;
            Ci[r][nn] = (signed char)Cm[(size_t)(b * LSEQ + z * CS + lhalf * 128 + r) * NDIM + nn];
        }
        __syncthreads();
        float acc[4][8];
#pragma unroll
        for (int i = 0; i < 4; ++i)
#pragma unroll
            for (int j = 0; j < 8; ++j) acc[i][j] = 0.f;
        for (int nn = 0; nn < 128; ++nn) {
            float pv[8];
#pragma unroll
            for (int j = 0; j < 8; ++j) pv[j] = prevT[nn][p0 + j];
#pragma unroll
            for (int i = 0; i < 4; ++i) {
                float c = (float)Ci[lrow + 32 * i][nn];
#pragma unroll
                for (int j = 0; j < 8; ++j) acc[i][j] += c * pv[j];
            }
        }
#pragma unroll
        for (int i = 0; i < 4; ++i) {
            int lloc = lhalf * 128 + lrow + 32 * i;
            float e = __expf(cum[base + lloc]) * Csc;
            size_t go = ((size_t)(b * LSEQ + z * CS + lloc) * H + h) * PDIM + p0;
            const int* xp = xq + go;
            float* op = out + go;
#pragma unroll
            for (int j = 0; j < 8; ++j)
                op[j] += e * acc[i][j] + (float)xp[j] * xs * Df;
        }
    }
}

extern "C" void kernel_launch(void* const* d_in, const int* in_sizes, int n_in,
                              void* d_out, int out_size, void* d_ws, size_t ws_size,
                              hipStream_t stream)
{
    const int* xq = (const int*)d_in[0];
    const int* dt = (const int*)d_in[1];
    const int* Bm = (const int*)d_in[2];
    const int* Cm = (const int*)d_in[3];
    const int* qA = (const int*)d_in[4];
    const int* qD = (const int*)d_in[5];
    const float* dt_bias = (const float*)d_in[6];
    const float* A_scale = (const float*)d_in[7];
    const float* D_scale = (const float*)d_in[8];
    const float* dt_scale = (const float*)d_in[9];
    const float* x_scale = (const float*)d_in[10];
    const float* B_scale = (const float*)d_in[11];
    const float* C_scale = (const float*)d_in[12];
    float* out = (float*)d_out;

    char* ws = (char*)d_ws;
    float* dtf    = (float*)(ws);
    float* cum    = (float*)(ws + 524288);
    float* cdecay = (float*)(ws + 1048576);
    float* CBf    = (float*)(ws + 1052672);
    float* states = (float*)(ws + 1052672 + 4194304);

    k1_dtcum<<<dim3(512), dim3(256), 0, stream>>>(dt, qA, dt_bias, A_scale, dt_scale,
                                                  dtf, cum, cdecay);
    k2_cb<<<dim3(256), dim3(256), 0, stream>>>(Bm, Cm, B_scale, C_scale, CBf);
    k3_states<<<dim3(512), dim3(256), 0, stream>>>(xq, Bm, x_scale, B_scale, dtf, cum, states);
    k4_scan<<<dim3(2048), dim3(256), 0, stream>>>(cdecay, states);
    k5_intra<<<dim3(512), dim3(256), 0, stream>>>(xq, CBf, dtf, cum, x_scale, out);
    k6_inter<<<dim3(512), dim3(256), 0, stream>>>(xq, Cm, qD, cum, states,
                                                  C_scale, x_scale, D_scale, out);
}

// Round 2
// 251.629 us; speedup vs baseline: 1.5820x; 1.5820x over previous
//
#include <hip/hip_runtime.h>
#include <math.h>

#define BB 2
#define LSEQ 2048
#define H 32
#define PDIM 64
#define NDIM 128
#define CS 256
#define NC 8

typedef _Float16 half8 __attribute__((ext_vector_type(8)));
typedef float floatx4 __attribute__((ext_vector_type(4)));

// ---------------- ws layout (bytes) ----------------
// dtf    : f32 [BB][NC][H][CS]          @ 0         (512 KB)
// cum    : f32 [BB][NC][H][CS]          @ 524288    (512 KB)
// cdecay : f32 [BB][NC][H]              @ 1048576   (2 KB)
// CBl    : f32 [BB][NC][CS(l)][CS(s)]   @ 1052672   (4 MB)  l-major, s fastest
// states : f32 [BB][NC][H][PDIM][NDIM]  @ 5246976   (16 MB)
// xTdt   : f16 [BB][NC][H][PDIM][CS]    @ 22024192  (16 MB)  x*dtf*x_scale
// xTc    : f16 [BB][NC][H][PDIM][CS]    @ 38801408  (16 MB)  x*dtf*decay*x_scale*B_scale
// Bt16   : f16 [BB][NC][NDIM][CS]       @ 55578624  (1 MB)   B transposed, raw

__device__ __forceinline__ int dot4i8(int a, int b, int c) {
#if __has_builtin(__builtin_amdgcn_sdot4)
    return __builtin_amdgcn_sdot4(a, b, c, false);
#else
    c += ((a << 24) >> 24) * ((b << 24) >> 24);
    c += ((a << 16) >> 24) * ((b << 16) >> 24);
    c += ((a << 8) >> 24) * ((b << 8) >> 24);
    c += (a >> 24) * (b >> 24);
    return c;
#endif
}

// K1: dtf = softplus(dt*scale+bias); cum = cumsum(dtf*A); cdecay = exp(cum[-1])
__global__ __launch_bounds__(256) void k1_dtcum(
    const int* __restrict__ dt, const int* __restrict__ qA,
    const float* __restrict__ dt_bias,
    const float* __restrict__ A_scale_p, const float* __restrict__ dt_scale_p,
    float* __restrict__ dtf, float* __restrict__ cum, float* __restrict__ cdecay)
{
    int t = threadIdx.x;
    int h = blockIdx.x & 31;
    int z = (blockIdx.x >> 5) & 7;
    int b = blockIdx.x >> 8;
    int l = z * CS + t;
    float dt_scale = *dt_scale_p;
    float A = -__expf((float)qA[h] * (*A_scale_p));
    float raw = (float)dt[(b * LSEQ + l) * H + h];
    float xin = raw * dt_scale + dt_bias[h];
    float sp = (xin > 20.f) ? xin : log1pf(__expf(xin));
    float dA = sp * A;

    __shared__ float arr[CS];
    arr[t] = dA;
    __syncthreads();
    for (int off = 1; off < CS; off <<= 1) {
        float v = (t >= off) ? arr[t - off] : 0.f;
        __syncthreads();
        arr[t] += v;
        __syncthreads();
    }
    int base = ((b * NC + z) * H + h) * CS;
    dtf[base + t] = sp;
    cum[base + t] = arr[t];
    if (t == CS - 1) cdecay[(b * NC + z) * H + h] = __expf(arr[t]);
}

// K2: CBl[b][z][l][s] = (C[l].B[s]) * B_scale*C_scale — only causal 64x64 tiles
__global__ __launch_bounds__(256) void k2_cb(
    const int* __restrict__ Bm, const int* __restrict__ Cm,
    const float* __restrict__ Bs_p, const float* __restrict__ Cs_p,
    float* __restrict__ CBl)
{
    __shared__ int Bi[64][33];
    __shared__ int Ci[64][33];
    const int LT[10] = {0,1,1,2,2,2,3,3,3,3};
    const int ST[10] = {0,0,1,0,1,2,0,1,2,3};
    int t = threadIdx.x;
    int tile = blockIdx.x % 10;
    int zz = blockIdx.x / 10;
    int z = zz & 7, b = zz >> 3;
    int l0 = LT[tile] * 64, s0 = ST[tile] * 64;
    const int* Bp = Bm + (size_t)(b * LSEQ + z * CS + s0) * NDIM;
    const int* Cp = Cm + (size_t)(b * LSEQ + z * CS + l0) * NDIM;
    for (int i = t; i < 64 * 32; i += 256) {
        int r = i >> 5, k = i & 31;
        const int* sb = Bp + r * NDIM + k * 4;
        const int* sc = Cp + r * NDIM + k * 4;
        Bi[r][k] = (sb[0] & 255) | ((sb[1] & 255) << 8) | ((sb[2] & 255) << 16) | ((sb[3] & 255) << 24);
        Ci[r][k] = (sc[0] & 255) | ((sc[1] & 255) << 8) | ((sc[2] & 255) << 16) | ((sc[3] & 255) << 24);
    }
    __syncthreads();
    float cbscale = (*Bs_p) * (*Cs_p);
    int ll = t & 63, lg = t >> 6;   // lg wave-uniform
    int acc[16];
#pragma unroll
    for (int i = 0; i < 16; ++i) acc[i] = 0;
    for (int k = 0; k < 32; ++k) {
        int cw = Ci[ll][k];
#pragma unroll
        for (int si = 0; si < 16; ++si)
            acc[si] = dot4i8(cw, Bi[lg * 16 + si][k], acc[si]);
    }
    float* outp = CBl + ((size_t)((b * NC + z) * CS + l0 + ll)) * CS + s0 + lg * 16;
#pragma unroll
    for (int si = 0; si < 16; ++si) outp[si] = (float)acc[si] * cbscale;
}

// K3prep: Bt16[b][z][n][s] = f16(B[s][n])  (head-independent, raw ints)
__global__ __launch_bounds__(256) void k3prep(
    const int* __restrict__ Bm, _Float16* __restrict__ Bt16)
{
    int t = threadIdx.x;
    int nt = blockIdx.x & 7, z = (blockIdx.x >> 3) & 7, b = blockIdx.x >> 6;
    int n0 = nt * 16;
    const int* bb = Bm + (size_t)(b * LSEQ + z * CS) * NDIM;
    _Float16* ob = Bt16 + (size_t)(b * NC + z) * NDIM * CS;
    for (int i = t; i < 16 * 32; i += 256) {
        int nl = i & 15, s8 = i >> 4;
        half8 v;
#pragma unroll
        for (int j = 0; j < 8; ++j)
            v[j] = (_Float16)(float)bb[(size_t)(s8 * 8 + j) * NDIM + n0 + nl];
        *(half8*)(ob + (size_t)(n0 + nl) * CS + s8 * 8) = v;
    }
}

// K0x: transpose x to [p][s] fp16, two variants with per-s coefficients folded
__global__ __launch_bounds__(256) void k0x(
    const int* __restrict__ xq, const float* __restrict__ dtf, const float* __restrict__ cum,
    const float* __restrict__ xs_p, const float* __restrict__ Bs_p,
    _Float16* __restrict__ xTdt, _Float16* __restrict__ xTc)
{
    __shared__ float cA[CS], cB[CS];
    int t = threadIdx.x;
    int h = blockIdx.x & 31, z = (blockIdx.x >> 5) & 7, b = blockIdx.x >> 8;
    int bz = b * NC + z;
    int base = (bz * H + h) * CS;
    float xs = *xs_p, Bs = *Bs_p;
    {
        float d = dtf[base + t], c = cum[base + t], cl = cum[base + CS - 1];
        cA[t] = d * xs;
        cB[t] = d * __expf(cl - c) * xs * Bs;
    }
    __syncthreads();
    int s8 = t & 31, pr = t >> 5;
    const int* xbase = xq + ((size_t)(b * LSEQ + z * CS) * H + h) * PDIM;
    size_t obase = (size_t)(bz * H + h) * PDIM * CS;
    for (int p = pr; p < PDIM; p += 8) {
        half8 va, vc;
#pragma unroll
        for (int j = 0; j < 8; ++j) {
            int s = s8 * 8 + j;
            float xv = (float)xbase[(size_t)s * (H * PDIM) + p];
            va[j] = (_Float16)(xv * cA[s]);
            vc[j] = (_Float16)(xv * cB[s]);
        }
        *(half8*)(xTdt + obase + (size_t)p * CS + s8 * 8) = va;
        *(half8*)(xTc + obase + (size_t)p * CS + s8 * 8) = vc;
    }
}

// K3m: states[p][n] = sum_s xTc[p][s] * Bt16[n][s]   (MFMA, per (b,z,h))
__global__ __launch_bounds__(256) void k3m(
    const _Float16* __restrict__ xTc, const _Float16* __restrict__ Bt16,
    float* __restrict__ states)
{
    int t = threadIdx.x;
    int h = blockIdx.x & 31, z = (blockIdx.x >> 5) & 7, b = blockIdx.x >> 8;
    int bz = b * NC + z;
    int w = t >> 6, lane = t & 63, m = lane & 15, q = lane >> 4;
    const _Float16* arow = xTc + ((size_t)(bz * H + h) * PDIM + w * 16 + m) * CS;
    const _Float16* brow = Bt16 + (size_t)bz * NDIM * CS;
    floatx4 acc[8] = {};
    for (int kk = 0; kk < 8; ++kk) {
        int sb = kk * 32 + q * 8;
        half8 a = *(const half8*)(arow + sb);
#pragma unroll
        for (int nt = 0; nt < 8; ++nt) {
            half8 bf = *(const half8*)(brow + (size_t)(nt * 16 + m) * CS + sb);
            acc[nt] = __builtin_amdgcn_mfma_f32_16x16x32_f16(a, bf, acc[nt], 0, 0, 0);
        }
    }
    float* sbase = states + (size_t)(bz * H + h) * PDIM * NDIM;
#pragma unroll
    for (int nt = 0; nt < 8; ++nt)
#pragma unroll
        for (int r = 0; r < 4; ++r) {
            int p = w * 16 + q * 4 + r;
            sbase[(size_t)p * NDIM + nt * 16 + m] = acc[nt][r];
        }
}

// K4: in-place inter-chunk scan over states [b][z][h][p][n]
__global__ __launch_bounds__(256) void k4_scan(
    const float* __restrict__ cdecay, float* __restrict__ states)
{
    int idx = blockIdx.x * 256 + threadIdx.x;
    int i = idx & 8191, h = (idx >> 13) & 31, b = idx >> 18;
    float carry = 0.f;
    for (int z = 0; z < NC; ++z) {
        size_t off = ((size_t)((b * NC + z) * H + h)) * 8192 + i;
        float v = states[off];
        float d = cdecay[(b * NC + z) * H + h];
        states[off] = carry;
        carry = d * carry + v;
    }
}

// K5m: y_intra = W @ xTdt via MFMA; W[l][s] = CBl[l][s]*exp(cum_l-cum_s), s<=l
__global__ __launch_bounds__(256) void k5m(
    const float* __restrict__ CBl, const _Float16* __restrict__ xTdt,
    const float* __restrict__ cum, float* __restrict__ out)
{
    int t = threadIdx.x;
    int lt = blockIdx.x & 3, h = (blockIdx.x >> 2) & 31;
    int z = (blockIdx.x >> 7) & 7, b = blockIdx.x >> 10;
    int bz = b * NC + z;
    __shared__ float cumL[CS];
    int base = (bz * H + h) * CS;
    cumL[t] = cum[base + t];
    __syncthreads();
    int w = t >> 6, lane = t & 63, m = lane & 15, q = lane >> 4;
    int lA = lt * 64 + w * 16 + m;
    float cum_l = cumL[lA];
    const float* cbrow = CBl + (size_t)(bz * CS + lA) * CS;
    const _Float16* xrow = xTdt + (size_t)(bz * H + h) * PDIM * CS;
    floatx4 acc[4] = {};
    int nk = 2 * lt + 1 + (w >> 1);          // tile-causal: skip all-masked k-steps
    for (int kk = 0; kk < nk; ++kk) {
        int sb = kk * 32 + q * 8;
        floatx4 cb0 = *(const floatx4*)(cbrow + sb);
        floatx4 cb1 = *(const floatx4*)(cbrow + sb + 4);
        half8 a;
#pragma unroll
        for (int j = 0; j < 8; ++j) {
            int s = sb + j;
            float cb = (j < 4) ? cb0[j & 3] : cb1[j & 3];
            float e = __expf(cum_l - cumL[s]);
            float wv = (s <= lA) ? cb * e : 0.f;
            a[j] = (_Float16)wv;
        }
#pragma unroll
        for (int pt = 0; pt < 4; ++pt) {
            half8 bf = *(const half8*)(xrow + (size_t)(pt * 16 + m) * CS + sb);
            acc[pt] = __builtin_amdgcn_mfma_f32_16x16x32_f16(a, bf, acc[pt], 0, 0, 0);
        }
    }
#pragma unroll
    for (int pt = 0; pt < 4; ++pt)
#pragma unroll
        for (int r = 0; r < 4; ++r) {
            int l = lt * 64 + w * 16 + q * 4 + r;
            int p = pt * 16 + m;
            out[((size_t)(b * LSEQ + z * CS + l) * H + h) * PDIM + p] = acc[pt][r];
        }
}

// K6m: out += exp(cum_l)*Cs * (C[l,:] @ prev[:,p]) + x*xs*D   (MFMA)
__global__ __launch_bounds__(256) void k6m(
    const int* __restrict__ xq, const int* __restrict__ Cm, const int* __restrict__ qD,
    const float* __restrict__ cum, const float* __restrict__ states,
    const float* __restrict__ Cs_p, const float* __restrict__ xs_p, const float* __restrict__ Ds_p,
    float* __restrict__ out)
{
    int t = threadIdx.x;
    int h = blockIdx.x & 31, z = (blockIdx.x >> 5) & 7, b = blockIdx.x >> 8;
    int bz = b * NC + z;
    int w = t >> 6, lane = t & 63, m = lane & 15, q = lane >> 4;
    floatx4 acc[4][4] = {};
    const float* srow = states + (size_t)(bz * H + h) * PDIM * NDIM;
    const int* crow = Cm + (size_t)(b * LSEQ + z * CS) * NDIM;
    for (int kk = 0; kk < 4; ++kk) {
        int nb = kk * 32 + q * 8;
        half8 bf[4];
#pragma unroll
        for (int pt = 0; pt < 4; ++pt) {
            const float* sp = srow + (size_t)(pt * 16 + m) * NDIM + nb;
            floatx4 v0 = *(const floatx4*)(sp);
            floatx4 v1 = *(const floatx4*)(sp + 4);
            half8 hb;
#pragma unroll
            for (int j = 0; j < 4; ++j) {
                hb[j] = (_Float16)(v0[j] * 0.0625f);       // 1/16 range guard
                hb[j + 4] = (_Float16)(v1[j] * 0.0625f);
            }
            bf[pt] = hb;
        }
#pragma unroll
        for (int mt = 0; mt < 4; ++mt) {
            int lA = w * 64 + mt * 16 + m;
            const int4* cp = (const int4*)(crow + (size_t)lA * NDIM + nb);
            int4 c0 = cp[0], c1 = cp[1];
            half8 ha;
            ha[0] = (_Float16)(float)c0.x; ha[1] = (_Float16)(float)c0.y;
            ha[2] = (_Float16)(float)c0.z; ha[3] = (_Float16)(float)c0.w;
            ha[4] = (_Float16)(float)c1.x; ha[5] = (_Float16)(float)c1.y;
            ha[6] = (_Float16)(float)c1.z; ha[7] = (_Float16)(float)c1.w;
#pragma unroll
            for (int pt = 0; pt < 4; ++pt)
                acc[mt][pt] = __builtin_amdgcn_mfma_f32_16x16x32_f16(ha, bf[pt], acc[mt][pt], 0, 0, 0);
        }
    }
    float Csc = (*Cs_p) * 16.0f, xs = *xs_p;
    float Df = (float)qD[h] * (*Ds_p);
    int cbase = (bz * H + h) * CS;
#pragma unroll
    for (int mt = 0; mt < 4; ++mt)
#pragma unroll
        for (int r = 0; r < 4; ++r) {
            int l = w * 64 + mt * 16 + q * 4 + r;
            float e = __expf(cum[cbase + l]) * Csc;
            size_t go = ((size_t)(b * LSEQ + z * CS + l) * H + h) * PDIM;
#pragma unroll
            for (int pt = 0; pt < 4; ++pt) {
                size_t off = go + pt * 16 + m;
                out[off] += e * acc[mt][pt][r] + (float)xq[off] * xs * Df;
            }
        }
}

extern "C" void kernel_launch(void* const* d_in, const int* in_sizes, int n_in,
                              void* d_out, int out_size, void* d_ws, size_t ws_size,
                              hipStream_t stream)
{
    const int* xq = (const int*)d_in[0];
    const int* dt = (const int*)d_in[1];
    const int* Bm = (const int*)d_in[2];
    const int* Cm = (const int*)d_in[3];
    const int* qA = (const int*)d_in[4];
    const int* qD = (const int*)d_in[5];
    const float* dt_bias = (const float*)d_in[6];
    const float* A_scale = (const float*)d_in[7];
    const float* D_scale = (const float*)d_in[8];
    const float* dt_scale = (const float*)d_in[9];
    const float* x_scale = (const float*)d_in[10];
    const float* B_scale = (const float*)d_in[11];
    const float* C_scale = (const float*)d_in[12];
    float* out = (float*)d_out;

    char* ws = (char*)d_ws;
    float* dtf        = (float*)(ws);
    float* cum        = (float*)(ws + 524288);
    float* cdecay     = (float*)(ws + 1048576);
    float* CBl        = (float*)(ws + 1052672);
    float* states     = (float*)(ws + 5246976);
    _Float16* xTdt    = (_Float16*)(ws + 22024192);
    _Float16* xTc     = (_Float16*)(ws + 38801408);
    _Float16* Bt16    = (_Float16*)(ws + 55578624);

    k1_dtcum<<<dim3(512), dim3(256), 0, stream>>>(dt, qA, dt_bias, A_scale, dt_scale,
                                                  dtf, cum, cdecay);
    k2_cb<<<dim3(160), dim3(256), 0, stream>>>(Bm, Cm, B_scale, C_scale, CBl);
    k3prep<<<dim3(128), dim3(256), 0, stream>>>(Bm, Bt16);
    k0x<<<dim3(512), dim3(256), 0, stream>>>(xq, dtf, cum, x_scale, B_scale, xTdt, xTc);
    k3m<<<dim3(512), dim3(256), 0, stream>>>(xTc, Bt16, states);
    k4_scan<<<dim3(2048), dim3(256), 0, stream>>>(cdecay, states);
    k5m<<<dim3(2048), dim3(256), 0, stream>>>(CBl, xTdt, cum, out);
    k6m<<<dim3(512), dim3(256), 0, stream>>>(xq, Cm, qD, cum, states,
                                             C_scale, x_scale, D_scale, out);
}

// Round 3
// 176.960 us; speedup vs baseline: 2.2495x; 1.4220x over previous
//
#include <hip/hip_runtime.h>
#include <math.h>

#define BB 2
#define LSEQ 2048
#define H 32
#define PDIM 64
#define NDIM 128
#define CS 256
#define NC 8

typedef _Float16 half8 __attribute__((ext_vector_type(8)));
typedef float floatx4 __attribute__((ext_vector_type(4)));

// ---------------- ws layout (bytes) ----------------
// dtf      : f32 [BB*NC][H][CS]               @ 0         (512 KB)
// cum      : f32 [BB*NC][H][CS]               @ 524288    (512 KB)
// cdecay   : f32 [BB*NC][H]                   @ 1048576   (2 KB)
// CBt      : f32 [bz][l16=16][s8=32][16][8]   @ 1052672   (4 MB)   MFMA-tiled
// states   : f32 [bzh][PDIM][NDIM]            @ 5246976   (16 MB)
// xTdtT    : f16 [bzh][p16=4][s8=32][16][8]   @ 22024192  (16 MB)  x*dtf*xs, tiled
// xTcT     : f16 [bzh][p16=4][s8=32][16][8]   @ 38801408  (16 MB)  +decay, tiled
//   statesHT (f16 [bzh][p16=4][n8=16][16][8], 8 MB) ALIASES xTcT @ 38801408
//   (k4 writes it strictly after k3m's last read of xTcT)
// Bt16T    : f16 [bz][n16=8][s8=32][16][8]    @ 55578624  (1 MB)
// C16T     : f16 [bz][l16=16][n8=16][16][8]   @ 56627200  (1 MB)

__device__ __forceinline__ int dot4i8(int a, int b, int c) {
#if __has_builtin(__builtin_amdgcn_sdot4)
    return __builtin_amdgcn_sdot4(a, b, c, false);
#else
    c += ((a << 24) >> 24) * ((b << 24) >> 24);
    c += ((a << 16) >> 24) * ((b << 16) >> 24);
    c += ((a << 8) >> 24) * ((b << 8) >> 24);
    c += (a >> 24) * (b >> 24);
    return c;
#endif
}

// K1: dtf = softplus(dt*scale+bias); cum = cumsum(dtf*A); cdecay = exp(cum[-1])
__global__ __launch_bounds__(256) void k1_dtcum(
    const int* __restrict__ dt, const int* __restrict__ qA,
    const float* __restrict__ dt_bias,
    const float* __restrict__ A_scale_p, const float* __restrict__ dt_scale_p,
    float* __restrict__ dtf, float* __restrict__ cum, float* __restrict__ cdecay)
{
    int t = threadIdx.x;
    int h = blockIdx.x & 31;
    int z = (blockIdx.x >> 5) & 7;
    int b = blockIdx.x >> 8;
    int l = z * CS + t;
    float dt_scale = *dt_scale_p;
    float A = -__expf((float)qA[h] * (*A_scale_p));
    float raw = (float)dt[(b * LSEQ + l) * H + h];
    float xin = raw * dt_scale + dt_bias[h];
    float sp = (xin > 20.f) ? xin : log1pf(__expf(xin));
    float dA = sp * A;

    __shared__ float arr[CS];
    arr[t] = dA;
    __syncthreads();
    for (int off = 1; off < CS; off <<= 1) {
        float v = (t >= off) ? arr[t - off] : 0.f;
        __syncthreads();
        arr[t] += v;
        __syncthreads();
    }
    int base = ((b * NC + z) * H + h) * CS;
    dtf[base + t] = sp;
    cum[base + t] = arr[t];
    if (t == CS - 1) cdecay[(b * NC + z) * H + h] = __expf(arr[t]);
}

// K2: CBt tiled = (C[l].B[s]) * Bs*Cs — only causal 64x64 blocks
__global__ __launch_bounds__(256) void k2_cb(
    const int* __restrict__ Bm, const int* __restrict__ Cm,
    const float* __restrict__ Bs_p, const float* __restrict__ Cs_p,
    float* __restrict__ CBt)
{
    __shared__ int Bi[64][33];
    __shared__ int Ci[64][33];
    const int LT[10] = {0,1,1,2,2,2,3,3,3,3};
    const int ST[10] = {0,0,1,0,1,2,0,1,2,3};
    int t = threadIdx.x;
    int tile = blockIdx.x % 10;
    int zz = blockIdx.x / 10;
    int z = zz & 7, b = zz >> 3;
    int bz = b * NC + z;
    int l0 = LT[tile] * 64, s0 = ST[tile] * 64;
    const int* Bp = Bm + (size_t)(b * LSEQ + z * CS + s0) * NDIM;
    const int* Cp = Cm + (size_t)(b * LSEQ + z * CS + l0) * NDIM;
    for (int i = t; i < 64 * 32; i += 256) {
        int r = i >> 5, k = i & 31;
        const int* sb = Bp + r * NDIM + k * 4;
        const int* sc = Cp + r * NDIM + k * 4;
        Bi[r][k] = (sb[0] & 255) | ((sb[1] & 255) << 8) | ((sb[2] & 255) << 16) | ((sb[3] & 255) << 24);
        Ci[r][k] = (sc[0] & 255) | ((sc[1] & 255) << 8) | ((sc[2] & 255) << 16) | ((sc[3] & 255) << 24);
    }
    __syncthreads();
    float cbscale = (*Bs_p) * (*Cs_p);
    int ll = t & 63, lg = t >> 6;   // lg wave-uniform
    int acc[16];
#pragma unroll
    for (int i = 0; i < 16; ++i) acc[i] = 0;
    for (int k = 0; k < 32; ++k) {
        int cw = Ci[ll][k];
#pragma unroll
        for (int si = 0; si < 16; ++si)
            acc[si] = dot4i8(cw, Bi[lg * 16 + si][k], acc[si]);
    }
    int l = l0 + ll;
    int l16 = l >> 4, lm = l & 15;
    int sb8 = (s0 + lg * 16) >> 3;
    float* bp = CBt + ((size_t)(bz * 16 + l16) * 32 + sb8) * 128 + lm * 8;
#pragma unroll
    for (int g = 0; g < 2; ++g) {
        floatx4 v0, v1;
#pragma unroll
        for (int i = 0; i < 4; ++i) {
            v0[i] = (float)acc[g * 8 + i] * cbscale;
            v1[i] = (float)acc[g * 8 + 4 + i] * cbscale;
        }
        *(floatx4*)(bp + g * 128) = v0;
        *(floatx4*)(bp + g * 128 + 4) = v1;
    }
}

// Kprep: Bt16T (transposed, tiled) + C16T (tiled) fp16, raw int values
__global__ __launch_bounds__(256) void kprep(
    const int* __restrict__ Bm, const int* __restrict__ Cm,
    _Float16* __restrict__ Bt16T, _Float16* __restrict__ C16T)
{
    int t = threadIdx.x;
    int slice = blockIdx.x & 15, z = (blockIdx.x >> 4) & 7, b = blockIdx.x >> 7;
    int bz = b * NC + z;
    {   // C: l16 = slice, no transpose needed (n-contiguous)
        int lm = t >> 4, n8 = t & 15;
        const int* cp = Cm + (size_t)(b * LSEQ + z * CS + slice * 16 + lm) * NDIM + n8 * 8;
        int4 c0 = *(const int4*)cp;
        int4 c1 = *(const int4*)(cp + 4);
        half8 v;
        v[0] = (_Float16)(float)c0.x; v[1] = (_Float16)(float)c0.y;
        v[2] = (_Float16)(float)c0.z; v[3] = (_Float16)(float)c0.w;
        v[4] = (_Float16)(float)c1.x; v[5] = (_Float16)(float)c1.y;
        v[6] = (_Float16)(float)c1.z; v[7] = (_Float16)(float)c1.w;
        *(half8*)(C16T + ((size_t)(bz * 16 + slice) * 16 + n8) * 128 + lm * 8) = v;
    }
    {   // B transpose: n16 = slice&7, s-half = slice>>3
        int nm = t & 15, s8l = t >> 4;
        int n16 = slice & 7, s8 = (slice >> 3) * 16 + s8l;
        const int* bp = Bm + (size_t)(b * LSEQ + z * CS + s8 * 8) * NDIM + n16 * 16 + nm;
        half8 v;
#pragma unroll
        for (int j = 0; j < 8; ++j) v[j] = (_Float16)(float)bp[(size_t)j * NDIM];
        *(half8*)(Bt16T + ((size_t)(bz * 8 + n16) * 32 + s8) * 128 + nm * 8) = v;
    }
}

// K0x: x -> tiled fp16 transposes with per-s coefficients folded
__global__ __launch_bounds__(256) void k0x(
    const int* __restrict__ xq, const float* __restrict__ dtf, const float* __restrict__ cum,
    const float* __restrict__ xs_p, const float* __restrict__ Bs_p,
    _Float16* __restrict__ xTdtT, _Float16* __restrict__ xTcT)
{
    __shared__ float cA[CS], cB[CS];
    int t = threadIdx.x;
    int h = blockIdx.x & 31, z = (blockIdx.x >> 5) & 7, b = blockIdx.x >> 8;
    int bzh = ((b * NC + z) * H + h);
    int base = bzh * CS;
    float xs = *xs_p, Bs = *Bs_p;
    {
        float d = dtf[base + t], c = cum[base + t], cl = cum[base + CS - 1];
        cA[t] = d * xs;
        cB[t] = d * __expf(cl - c) * xs * Bs;
    }
    __syncthreads();
    int s8 = t & 31, pg = t >> 5;             // p-group of 8
    const int* xb = xq + ((size_t)(b * LSEQ + z * CS) * H + h) * PDIM + pg * 8;
    half8 va[8], vc[8];
#pragma unroll
    for (int j = 0; j < 8; ++j) {
        int s = s8 * 8 + j;
        const int* xp = xb + (size_t)s * (H * PDIM);
        int4 lo = *(const int4*)xp;
        int4 hi = *(const int4*)(xp + 4);
        float a = cA[s], c = cB[s];
#define CVT(PL, V) { float xv = (float)(V); va[PL][j] = (_Float16)(xv * a); vc[PL][j] = (_Float16)(xv * c); }
        CVT(0, lo.x) CVT(1, lo.y) CVT(2, lo.z) CVT(3, lo.w)
        CVT(4, hi.x) CVT(5, hi.y) CVT(6, hi.z) CVT(7, hi.w)
#undef CVT
    }
    int p16 = pg >> 1;
#pragma unroll
    for (int pl = 0; pl < 8; ++pl) {
        int p = pg * 8 + pl;
        size_t off = ((size_t)(bzh * 4 + p16) * 32 + s8) * 128 + (p & 15) * 8;
        *(half8*)(xTdtT + off) = va[pl];
        *(half8*)(xTcT + off) = vc[pl];
    }
}

// K3m: states[p][n] = sum_s xTc[p][s] * B[s][n]  (MFMA, tiled operands, decay skip)
__global__ __launch_bounds__(256) void k3m(
    const _Float16* __restrict__ xTcT, const _Float16* __restrict__ Bt16T,
    const float* __restrict__ cum, float* __restrict__ states)
{
    __shared__ float cume[8];
    int t = threadIdx.x;
    int h = blockIdx.x & 31, z = (blockIdx.x >> 5) & 7, b = blockIdx.x >> 8;
    int bz = b * NC + z, bzh = bz * H + h;
    if (t < 8) cume[t] = cum[bzh * CS + t * 32 + 31];
    __syncthreads();
    float cl = cume[7];
    int w = t >> 6, lane = t & 63, m = lane & 15, q = lane >> 4;
    const _Float16* abase = xTcT + ((size_t)(bzh * 4 + w) * 32) * 128 + m * 8;
    const _Float16* bbase = Bt16T + (size_t)(bz * 8) * 32 * 128 + m * 8;
    floatx4 acc[8] = {};
    for (int kk = 0; kk < 8; ++kk) {
        if (cl - cume[kk] < -30.f) continue;   // whole chunk underflows fp16 -> exact 0
        int s8 = kk * 4 + q;
        half8 a = *(const half8*)(abase + (size_t)s8 * 128);
#pragma unroll
        for (int nt = 0; nt < 8; ++nt) {
            half8 bf = *(const half8*)(bbase + ((size_t)nt * 32 + s8) * 128);
            acc[nt] = __builtin_amdgcn_mfma_f32_16x16x32_f16(a, bf, acc[nt], 0, 0, 0);
        }
    }
    float* sb = states + (size_t)bzh * (PDIM * NDIM);
#pragma unroll
    for (int nt = 0; nt < 8; ++nt)
#pragma unroll
        for (int r = 0; r < 4; ++r)
            sb[(size_t)(w * 16 + q * 4 + r) * NDIM + nt * 16 + m] = acc[nt][r];
}

// K4: sequential inter-chunk scan; emits fp16 tiled statesHT (prev-state, /16)
__global__ __launch_bounds__(256) void k4_scan(
    const float* __restrict__ cdecay, const float* __restrict__ states,
    _Float16* __restrict__ statesHT)
{
    int idx = blockIdx.x * 256 + threadIdx.x;
    int i = idx & 8191, h = (idx >> 13) & 31, b = idx >> 18;
    int p = i >> 7, n = i & 127;
    int toff = ((p >> 4) * 16 + (n >> 3)) * 128 + (p & 15) * 8 + (n & 7);
    float carry = 0.f;
    for (int z = 0; z < NC; ++z) {
        int bzh = (b * NC + z) * H + h;
        float v = states[(size_t)bzh * 8192 + i];
        float d = cdecay[bzh];
        statesHT[(size_t)bzh * 8192 + toff] = (_Float16)(carry * 0.0625f);
        carry = d * carry + v;
    }
}

// K56: fused inter+intra+D per (b,z,h). Wave w owns l-tiles {w,4+w,8+w,12+w}.
__global__ __launch_bounds__(256) void k56(
    const int* __restrict__ xq, const int* __restrict__ qD,
    const float* __restrict__ cum, const float* __restrict__ CBt,
    const _Float16* __restrict__ xTdtT, const _Float16* __restrict__ C16T,
    const _Float16* __restrict__ statesHT,
    const float* __restrict__ Cs_p, const float* __restrict__ xs_p, const float* __restrict__ Ds_p,
    float* __restrict__ out)
{
    __shared__ float cumL[CS];
    __shared__ float ep[128][65];
    int t = threadIdx.x;
    int h = blockIdx.x & 31, z = (blockIdx.x >> 5) & 7, b = blockIdx.x >> 8;
    int bz = b * NC + z, bzh = bz * H + h;
    cumL[t] = cum[bzh * CS + t];
    __syncthreads();
    int w = t >> 6, lane = t & 63, m = lane & 15, q = lane >> 4;
    floatx4 acc[4][4] = {};   // [j][pt]

    // ---- inter phase: acc = C_raw @ (prev/16) ----
    const _Float16* shb = statesHT + (size_t)bzh * 8192 + m * 8;
    const _Float16* cbase = C16T + (size_t)bz * 16 * 16 * 128 + m * 8;
    bool interact[4];
#pragma unroll
    for (int j = 0; j < 4; ++j) interact[j] = (cumL[(4 * j + w) * 16] > -80.f);
    for (int kk = 0; kk < 4; ++kk) {
        int n8 = kk * 4 + q;
        half8 bf[4];
#pragma unroll
        for (int pt = 0; pt < 4; ++pt)
            bf[pt] = *(const half8*)(shb + (pt * 16 + n8) * 128);
#pragma unroll
        for (int j = 0; j < 4; ++j) {
            if (!interact[j]) continue;
            half8 ha = *(const half8*)(cbase + ((size_t)(4 * j + w) * 16 + n8) * 128);
#pragma unroll
            for (int pt = 0; pt < 4; ++pt)
                acc[j][pt] = __builtin_amdgcn_mfma_f32_16x16x32_f16(ha, bf[pt], acc[j][pt], 0, 0, 0);
        }
    }
    // scale inter rows by exp(cum_l)*Cs*16 -> becomes C-init for intra
    float Cs16 = (*Cs_p) * 16.0f;
#pragma unroll
    for (int j = 0; j < 4; ++j)
#pragma unroll
        for (int r = 0; r < 4; ++r) {
            float e = __expf(cumL[(4 * j + w) * 16 + q * 4 + r]) * Cs16;
#pragma unroll
            for (int pt = 0; pt < 4; ++pt) acc[j][pt][r] *= e;
        }

    // ---- intra phase ----
    const float* cbtb = CBt + (size_t)bz * 16 * 32 * 128 + m * 8;
    const _Float16* xb = xTdtT + (size_t)bzh * 4 * 32 * 128 + m * 8;
    for (int kk = 0; kk < 8; ++kk) {
        int jmin = (2 * kk - w + 3) >> 2;
        if (jmin < 0) jmin = 0;
        if (jmin > 3) continue;
        int s8 = kk * 4 + q;
        half8 bf[4];
#pragma unroll
        for (int pt = 0; pt < 4; ++pt)
            bf[pt] = *(const half8*)(xb + ((size_t)pt * 32 + s8) * 128);
        float cs_hi = cumL[kk * 32 + 31];
#pragma unroll
        for (int j = 0; j < 4; ++j) {
            if (j < jmin) continue;
            int l16 = 4 * j + w;
            if (cumL[l16 * 16] - cs_hi < -30.f) continue;   // fp16 exact-0 weights
            int lA = l16 * 16 + m;
            float cum_l = cumL[lA];
            const float* cp = cbtb + ((size_t)l16 * 32 + s8) * 128;
            floatx4 c0 = *(const floatx4*)cp;
            floatx4 c1 = *(const floatx4*)(cp + 4);
            half8 a;
#pragma unroll
            for (int jj = 0; jj < 8; ++jj) {
                int s = kk * 32 + q * 8 + jj;
                float cb = (jj < 4) ? c0[jj] : c1[jj - 4];
                float wv = cb * __expf(cum_l - cumL[s]);
                a[jj] = (_Float16)((s <= lA) ? wv : 0.f);
            }
#pragma unroll
            for (int pt = 0; pt < 4; ++pt)
                acc[j][pt] = __builtin_amdgcn_mfma_f32_16x16x32_f16(a, bf[pt], acc[j][pt], 0, 0, 0);
        }
    }

    // ---- epilogue: LDS transpose -> coalesced float4 out, + D*x ----
    float xsDf = (*xs_p) * ((float)qD[h] * (*Ds_p));
    __syncthreads();
#pragma unroll
    for (int pass = 0; pass < 2; ++pass) {
#pragma unroll
        for (int jj = 0; jj < 2; ++jj) {
            int j = pass * 2 + jj;
            int lbase = (((4 * j + w) * 16) & 127) + q * 4;
#pragma unroll
            for (int r = 0; r < 4; ++r)
#pragma unroll
                for (int pt = 0; pt < 4; ++pt)
                    ep[lbase + r][pt * 16 + m] = acc[j][pt][r];
        }
        __syncthreads();
        int lloc = t >> 1;
        int l = pass * 128 + lloc;
        size_t go = ((size_t)(b * LSEQ + z * CS + l) * H + h) * PDIM + (t & 1) * 32;
        const float* er = &ep[lloc][(t & 1) * 32];
#pragma unroll
        for (int it = 0; it < 8; ++it) {
            int4 xv = *(const int4*)(xq + go + it * 4);
            floatx4 v;
            v[0] = er[it * 4 + 0] + (float)xv.x * xsDf;
            v[1] = er[it * 4 + 1] + (float)xv.y * xsDf;
            v[2] = er[it * 4 + 2] + (float)xv.z * xsDf;
            v[3] = er[it * 4 + 3] + (float)xv.w * xsDf;
            *(floatx4*)(out + go + it * 4) = v;
        }
        __syncthreads();
    }
}

extern "C" void kernel_launch(void* const* d_in, const int* in_sizes, int n_in,
                              void* d_out, int out_size, void* d_ws, size_t ws_size,
                              hipStream_t stream)
{
    const int* xq = (const int*)d_in[0];
    const int* dt = (const int*)d_in[1];
    const int* Bm = (const int*)d_in[2];
    const int* Cm = (const int*)d_in[3];
    const int* qA = (const int*)d_in[4];
    const int* qD = (const int*)d_in[5];
    const float* dt_bias = (const float*)d_in[6];
    const float* A_scale = (const float*)d_in[7];
    const float* D_scale = (const float*)d_in[8];
    const float* dt_scale = (const float*)d_in[9];
    const float* x_scale = (const float*)d_in[10];
    const float* B_scale = (const float*)d_in[11];
    const float* C_scale = (const float*)d_in[12];
    float* out = (float*)d_out;

    char* ws = (char*)d_ws;
    float* dtf          = (float*)(ws);
    float* cum          = (float*)(ws + 524288);
    float* cdecay       = (float*)(ws + 1048576);
    float* CBt          = (float*)(ws + 1052672);
    float* states       = (float*)(ws + 5246976);
    _Float16* xTdtT     = (_Float16*)(ws + 22024192);
    _Float16* xTcT      = (_Float16*)(ws + 38801408);
    _Float16* statesHT  = (_Float16*)(ws + 38801408);  // aliases xTcT (k4 after k3m)
    _Float16* Bt16T     = (_Float16*)(ws + 55578624);
    _Float16* C16T      = (_Float16*)(ws + 56627200);

    k1_dtcum<<<dim3(512), dim3(256), 0, stream>>>(dt, qA, dt_bias, A_scale, dt_scale,
                                                  dtf, cum, cdecay);
    k2_cb<<<dim3(160), dim3(256), 0, stream>>>(Bm, Cm, B_scale, C_scale, CBt);
    kprep<<<dim3(256), dim3(256), 0, stream>>>(Bm, Cm, Bt16T, C16T);
    k0x<<<dim3(512), dim3(256), 0, stream>>>(xq, dtf, cum, x_scale, B_scale, xTdtT, xTcT);
    k3m<<<dim3(512), dim3(256), 0, stream>>>(xTcT, Bt16T, cum, states);
    k4_scan<<<dim3(2048), dim3(256), 0, stream>>>(cdecay, states, statesHT);
    k56<<<dim3(512), dim3(256), 0, stream>>>(xq, qD, cum, CBt, xTdtT, C16T, statesHT,
                                             C_scale, x_scale, D_scale, out);
}

// Round 4
// 163.537 us; speedup vs baseline: 2.4341x; 1.0821x over previous
//
#include <hip/hip_runtime.h>
#include <math.h>

#define BB 2
#define LSEQ 2048
#define H 32
#define PDIM 64
#define NDIM 128
#define CS 256
#define NC 8

typedef _Float16 half8 __attribute__((ext_vector_type(8)));
typedef _Float16 half4 __attribute__((ext_vector_type(4)));
typedef float floatx4 __attribute__((ext_vector_type(4)));

// ---------------- ws layout (bytes) ----------------
// cum      : f32 [bz=16][H][CS]               @ 0          (512 KB)
// cdecay   : f32 [bz][H]                      @ 524288     (2 KB)
// CBt      : f32 [bz][l16=16][s8=32][16][8]   @ 526336     (4 MB)   MFMA-tiled
// states   : f32 [bzh=512][PDIM][NDIM]        @ 4720640    (16 MB)
// xTdtT    : f16 [bzh][p16=4][s8=32][16][8]   @ 21497856   (16 MB)  x*dtf*xs, tiled
// statesHT : f16 [bzh][p16=4][n8=16][16][8]   @ 38275072   (8 MB)   prev-state/16
// Bt16T    : f16 [bz][n16=8][s8=32][16][8]    @ 46663680   (1 MB)
// C16T     : f16 [bz][l16=16][n8=16][16][8]   @ 47712256   (1 MB)
// x8       : i8  [b][l][h][p]                 @ 48760832   (8 MB)

__device__ __forceinline__ int dot4i8(int a, int b, int c) {
#if __has_builtin(__builtin_amdgcn_sdot4)
    return __builtin_amdgcn_sdot4(a, b, c, false);
#else
    c += ((a << 24) >> 24) * ((b << 24) >> 24);
    c += ((a << 16) >> 24) * ((b << 16) >> 24);
    c += ((a << 8) >> 24) * ((b << 8) >> 24);
    c += (a >> 24) * (b >> 24);
    return c;
#endif
}

// kA: merged k2 (CBt Gram, causal tiles) + kprep (Bt16T, C16T)
__global__ __launch_bounds__(256) void kA(
    const int* __restrict__ Bm, const int* __restrict__ Cm,
    const float* __restrict__ Bs_p, const float* __restrict__ Cs_p,
    float* __restrict__ CBt, _Float16* __restrict__ Bt16T, _Float16* __restrict__ C16T)
{
    __shared__ int Bi[64][33];
    __shared__ int Ci[64][33];
    int t = threadIdx.x;
    int r = blockIdx.x % 26;
    int zz = blockIdx.x / 26;
    int z = zz & 7, b = zz >> 3;
    int bz = b * NC + z;
    if (r < 10) {
        const int LT[10] = {0,1,1,2,2,2,3,3,3,3};
        const int ST[10] = {0,0,1,0,1,2,0,1,2,3};
        int l0 = LT[r] * 64, s0 = ST[r] * 64;
        const int* Bp = Bm + (size_t)(b * LSEQ + z * CS + s0) * NDIM;
        const int* Cp = Cm + (size_t)(b * LSEQ + z * CS + l0) * NDIM;
        for (int i = t; i < 64 * 32; i += 256) {
            int rr = i >> 5, k = i & 31;
            const int* sb = Bp + rr * NDIM + k * 4;
            const int* sc = Cp + rr * NDIM + k * 4;
            Bi[rr][k] = (sb[0] & 255) | ((sb[1] & 255) << 8) | ((sb[2] & 255) << 16) | ((sb[3] & 255) << 24);
            Ci[rr][k] = (sc[0] & 255) | ((sc[1] & 255) << 8) | ((sc[2] & 255) << 16) | ((sc[3] & 255) << 24);
        }
        __syncthreads();
        float cbscale = (*Bs_p) * (*Cs_p);
        int ll = t & 63, lg = t >> 6;
        int acc[16];
#pragma unroll
        for (int i = 0; i < 16; ++i) acc[i] = 0;
        for (int k = 0; k < 32; ++k) {
            int cw = Ci[ll][k];
#pragma unroll
            for (int si = 0; si < 16; ++si)
                acc[si] = dot4i8(cw, Bi[lg * 16 + si][k], acc[si]);
        }
        int l = l0 + ll;
        int l16 = l >> 4, lm = l & 15;
        int sb8 = (s0 + lg * 16) >> 3;
        float* bp = CBt + ((size_t)(bz * 16 + l16) * 32 + sb8) * 128 + lm * 8;
#pragma unroll
        for (int g = 0; g < 2; ++g) {
            floatx4 v0, v1;
#pragma unroll
            for (int i = 0; i < 4; ++i) {
                v0[i] = (float)acc[g * 8 + i] * cbscale;
                v1[i] = (float)acc[g * 8 + 4 + i] * cbscale;
            }
            *(floatx4*)(bp + g * 128) = v0;
            *(floatx4*)(bp + g * 128 + 4) = v1;
        }
    } else {
        int slice = r - 10;   // 0..15
        {   // C16T: l16 = slice
            int lm = t >> 4, n8 = t & 15;
            const int* cp = Cm + (size_t)(b * LSEQ + z * CS + slice * 16 + lm) * NDIM + n8 * 8;
            int4 c0 = *(const int4*)cp;
            int4 c1 = *(const int4*)(cp + 4);
            half8 v;
            v[0] = (_Float16)(float)c0.x; v[1] = (_Float16)(float)c0.y;
            v[2] = (_Float16)(float)c0.z; v[3] = (_Float16)(float)c0.w;
            v[4] = (_Float16)(float)c1.x; v[5] = (_Float16)(float)c1.y;
            v[6] = (_Float16)(float)c1.z; v[7] = (_Float16)(float)c1.w;
            *(half8*)(C16T + ((size_t)(bz * 16 + slice) * 16 + n8) * 128 + lm * 8) = v;
        }
        {   // Bt16T transpose: n16 = slice&7, s-half = slice>>3
            int nm = t & 15, s8l = t >> 4;
            int n16 = slice & 7, s8 = (slice >> 3) * 16 + s8l;
            const int* bp = Bm + (size_t)(b * LSEQ + z * CS + s8 * 8) * NDIM + n16 * 16 + nm;
            half8 v;
#pragma unroll
            for (int j = 0; j < 8; ++j) v[j] = (_Float16)(float)bp[(size_t)j * NDIM];
            *(half8*)(Bt16T + ((size_t)(bz * 8 + n16) * 32 + s8) * 128 + nm * 8) = v;
        }
    }
}

// k013: fused dt-softplus/cumsum + x transpose/quant-fold + states MFMA, per (b,z,h)
#define XC_PITCH 132    // 128 + 4 halfs pad -> 2-way (free) LDS bank aliasing
__global__ __launch_bounds__(256) void k013(
    const int* __restrict__ dt, const int* __restrict__ qA, const float* __restrict__ dt_bias,
    const float* __restrict__ A_scale_p, const float* __restrict__ dt_scale_p,
    const int* __restrict__ xq, const float* __restrict__ xs_p, const float* __restrict__ Bs_p,
    const _Float16* __restrict__ Bt16T,
    float* __restrict__ cum, float* __restrict__ cdecay,
    _Float16* __restrict__ xTdtT, signed char* __restrict__ x8,
    float* __restrict__ states)
{
    __shared__ float cumS[CS];
    __shared__ float cA[CS], cB[CS];
    __shared__ float wsum[4];
    __shared__ _Float16 xcS[4 * 32 * XC_PITCH];
    int t = threadIdx.x;
    int h = blockIdx.x & 31, z = (blockIdx.x >> 5) & 7, b = blockIdx.x >> 8;
    int bz = b * NC + z, bzh = bz * H + h;
    int lane6 = t & 63, w = t >> 6;

    // --- softplus + wave-shuffle inclusive scan ---
    float A = -__expf((float)qA[h] * (*A_scale_p));
    float raw = (float)dt[(size_t)(b * LSEQ + z * CS + t) * H + h];
    float xin = raw * (*dt_scale_p) + dt_bias[h];
    float sp = (xin > 20.f) ? xin : log1pf(__expf(xin));
    float v = sp * A;
#pragma unroll
    for (int off = 1; off < 64; off <<= 1) {
        float u = __shfl_up(v, off, 64);
        if (lane6 >= off) v += u;
    }
    if (lane6 == 63) wsum[w] = v;
    __syncthreads();
    float add = 0.f;
    for (int wv = 0; wv < w; ++wv) add += wsum[wv];
    float cumv = v + add;
    float cl = wsum[0] + wsum[1] + wsum[2] + wsum[3];
    float xs = *xs_p;
    cum[bzh * CS + t] = cumv;
    if (t == 0) cdecay[bzh] = __expf(cl);
    cumS[t] = cumv;
    cA[t] = sp * xs;
    cB[t] = sp * __expf(cl - cumv) * xs * (*Bs_p);
    __syncthreads();

    // --- x load/transpose: xTdt -> global, xTc -> LDS, x8 -> global ---
    int s8 = t & 31, pg = t >> 5;
    const int* xb = xq + ((size_t)(b * LSEQ + z * CS) * H + h) * PDIM + pg * 8;
    {
        half8 va[8], vc[8];
        signed char pk[8][8];
#pragma unroll
        for (int j = 0; j < 8; ++j) {
            int s = s8 * 8 + j;
            const int* xp = xb + (size_t)s * (H * PDIM);
            int4 lo = *(const int4*)xp;
            int4 hi = *(const int4*)(xp + 4);
            float a = cA[s], c = cB[s];
#define CVT(PL, V) { float xv = (float)(V); va[PL][j] = (_Float16)(xv * a); vc[PL][j] = (_Float16)(xv * c); pk[j][PL] = (signed char)(V); }
            CVT(0, lo.x) CVT(1, lo.y) CVT(2, lo.z) CVT(3, lo.w)
            CVT(4, hi.x) CVT(5, hi.y) CVT(6, hi.z) CVT(7, hi.w)
#undef CVT
        }
        int p16 = pg >> 1;
#pragma unroll
        for (int pl = 0; pl < 8; ++pl) {
            int p = pg * 8 + pl;
            *(half8*)(xTdtT + ((size_t)(bzh * 4 + p16) * 32 + s8) * 128 + (p & 15) * 8) = va[pl];
            xcS[(p16 * 32 + s8) * XC_PITCH + (p & 15) * 8 + 0] = vc[pl][0];
        }
        // vc LDS store, vectorized per (p16,s8,pm): rewrite as half8 stores
#pragma unroll
        for (int pl = 0; pl < 8; ++pl) {
            int p = pg * 8 + pl;
            *(half8*)(xcS + (p16 * 32 + s8) * XC_PITCH + (p & 15) * 8) = vc[pl];
        }
        signed char* x8b = x8 + ((size_t)(b * LSEQ + z * CS) * H + h) * PDIM + pg * 8;
#pragma unroll
        for (int j = 0; j < 8; ++j)
            *(int2*)(x8b + (size_t)(s8 * 8 + j) * (H * PDIM)) = *(int2*)pk[j];
    }
    __syncthreads();

    // --- states MFMA: states[p][n] = sum_s xc[p][s]*B[s][n] ---
    int m = lane6 & 15, q = lane6 >> 4;
    const _Float16* bbase = Bt16T + (size_t)(bz * 8) * 32 * 128 + m * 8;
    const _Float16* abase = xcS + (w * 32) * XC_PITCH + m * 8;
    floatx4 acc[8] = {};
    for (int kk = 0; kk < 8; ++kk) {
        if (cl - cumS[kk * 32 + 31] < -30.f) continue;   // fp16-exact-0 chunk skip
        int s8k = kk * 4 + q;
        half8 a = *(const half8*)(abase + s8k * XC_PITCH);
#pragma unroll
        for (int nt = 0; nt < 8; ++nt) {
            half8 bf = *(const half8*)(bbase + ((size_t)nt * 32 + s8k) * 128);
            acc[nt] = __builtin_amdgcn_mfma_f32_16x16x32_f16(a, bf, acc[nt], 0, 0, 0);
        }
    }
    float* sb = states + (size_t)bzh * (PDIM * NDIM);
#pragma unroll
    for (int nt = 0; nt < 8; ++nt)
#pragma unroll
        for (int rr = 0; rr < 4; ++rr)
            sb[(size_t)(w * 16 + q * 4 + rr) * NDIM + nt * 16 + m] = acc[nt][rr];
}

// k4: sequential inter-chunk scan (float4), emits fp16 tiled statesHT (prev/16)
__global__ __launch_bounds__(256) void k4_scan(
    const float* __restrict__ cdecay, const float* __restrict__ states,
    _Float16* __restrict__ statesHT)
{
    int idx = blockIdx.x * 256 + threadIdx.x;
    int n4 = (idx & 31) * 4, p = (idx >> 5) & 63, h = (idx >> 11) & 31, b = idx >> 16;
    int soff = p * 128 + n4;
    int toff = ((p >> 4) * 16 + (n4 >> 3)) * 128 + (p & 15) * 8 + (n4 & 7);
    floatx4 carry = {};
    for (int z = 0; z < NC; ++z) {
        int bzh = (b * NC + z) * H + h;
        floatx4 v = *(const floatx4*)(states + (size_t)bzh * 8192 + soff);
        float d = cdecay[bzh];
        half4 o;
#pragma unroll
        for (int i = 0; i < 4; ++i) o[i] = (_Float16)(carry[i] * 0.0625f);
        *(half4*)(statesHT + (size_t)bzh * 8192 + toff) = o;
#pragma unroll
        for (int i = 0; i < 4; ++i) carry[i] = d * carry[i] + v[i];
    }
}

// k56: fused inter+intra+D per (b,z,h). Wave w owns l-tiles {w,4+w,8+w,12+w}.
__global__ __launch_bounds__(256) void k56(
    const signed char* __restrict__ x8, const int* __restrict__ qD,
    const float* __restrict__ cum, const float* __restrict__ CBt,
    const _Float16* __restrict__ xTdtT, const _Float16* __restrict__ C16T,
    const _Float16* __restrict__ statesHT,
    const float* __restrict__ Cs_p, const float* __restrict__ xs_p, const float* __restrict__ Ds_p,
    float* __restrict__ out)
{
    __shared__ float cumL[CS];
    __shared__ float ep[128][65];
    int t = threadIdx.x;
    int h = blockIdx.x & 31, z = (blockIdx.x >> 5) & 7, b = blockIdx.x >> 8;
    int bz = b * NC + z, bzh = bz * H + h;
    cumL[t] = cum[bzh * CS + t];
    __syncthreads();
    int w = t >> 6, lane = t & 63, m = lane & 15, q = lane >> 4;
    floatx4 acc[4][4] = {};   // [j][pt]

    // ---- inter phase: acc = C_raw @ (prev/16) ----
    const _Float16* shb = statesHT + (size_t)bzh * 8192 + m * 8;
    const _Float16* cbase = C16T + (size_t)bz * 16 * 16 * 128 + m * 8;
    bool interact[4];
#pragma unroll
    for (int j = 0; j < 4; ++j) interact[j] = (cumL[(4 * j + w) * 16] > -80.f);
    for (int kk = 0; kk < 4; ++kk) {
        int n8 = kk * 4 + q;
        half8 bf[4];
#pragma unroll
        for (int pt = 0; pt < 4; ++pt)
            bf[pt] = *(const half8*)(shb + (pt * 16 + n8) * 128);
#pragma unroll
        for (int j = 0; j < 4; ++j) {
            if (!interact[j]) continue;
            half8 ha = *(const half8*)(cbase + ((size_t)(4 * j + w) * 16 + n8) * 128);
#pragma unroll
            for (int pt = 0; pt < 4; ++pt)
                acc[j][pt] = __builtin_amdgcn_mfma_f32_16x16x32_f16(ha, bf[pt], acc[j][pt], 0, 0, 0);
        }
    }
    float Cs16 = (*Cs_p) * 16.0f;
#pragma unroll
    for (int j = 0; j < 4; ++j)
#pragma unroll
        for (int r = 0; r < 4; ++r) {
            float e = __expf(cumL[(4 * j + w) * 16 + q * 4 + r]) * Cs16;
#pragma unroll
            for (int pt = 0; pt < 4; ++pt) acc[j][pt][r] *= e;
        }

    // ---- intra phase ----
    const float* cbtb = CBt + (size_t)bz * 16 * 32 * 128 + m * 8;
    const _Float16* xb = xTdtT + (size_t)bzh * 4 * 32 * 128 + m * 8;
    for (int kk = 0; kk < 8; ++kk) {
        int jmin = (2 * kk - w + 3) >> 2;
        if (jmin < 0) jmin = 0;
        if (jmin > 3) continue;
        int s8 = kk * 4 + q;
        half8 bf[4];
#pragma unroll
        for (int pt = 0; pt < 4; ++pt)
            bf[pt] = *(const half8*)(xb + ((size_t)pt * 32 + s8) * 128);
        float cs_hi = cumL[kk * 32 + 31];
#pragma unroll
        for (int j = 0; j < 4; ++j) {
            if (j < jmin) continue;
            int l16 = 4 * j + w;
            if (cumL[l16 * 16] - cs_hi < -30.f) continue;
            int lA = l16 * 16 + m;
            float cum_l = cumL[lA];
            const float* cp = cbtb + ((size_t)l16 * 32 + s8) * 128;
            floatx4 c0 = *(const floatx4*)cp;
            floatx4 c1 = *(const floatx4*)(cp + 4);
            half8 a;
#pragma unroll
            for (int jj = 0; jj < 8; ++jj) {
                int s = kk * 32 + q * 8 + jj;
                float cb = (jj < 4) ? c0[jj] : c1[jj - 4];
                float wv = cb * __expf(cum_l - cumL[s]);
                a[jj] = (_Float16)((s <= lA) ? wv : 0.f);
            }
#pragma unroll
            for (int pt = 0; pt < 4; ++pt)
                acc[j][pt] = __builtin_amdgcn_mfma_f32_16x16x32_f16(a, bf[pt], acc[j][pt], 0, 0, 0);
        }
    }

    // ---- epilogue: LDS transpose -> coalesced float4 out, + D*x ----
    float xsDf = (*xs_p) * ((float)qD[h] * (*Ds_p));
    __syncthreads();
#pragma unroll
    for (int pass = 0; pass < 2; ++pass) {
#pragma unroll
        for (int jj = 0; jj < 2; ++jj) {
            int j = pass * 2 + jj;
            int lbase = (((4 * j + w) * 16) & 127) + q * 4;
#pragma unroll
            for (int r = 0; r < 4; ++r)
#pragma unroll
                for (int pt = 0; pt < 4; ++pt)
                    ep[lbase + r][pt * 16 + m] = acc[j][pt][r];
        }
        __syncthreads();
        int lloc = t >> 1;
        int l = pass * 128 + lloc;
        size_t go = ((size_t)(b * LSEQ + z * CS + l) * H + h) * PDIM + (t & 1) * 32;
        const float* er = &ep[lloc][(t & 1) * 32];
        const signed char* xp8 = x8 + go;
#pragma unroll
        for (int it = 0; it < 8; ++it) {
            int xw = *(const int*)(xp8 + it * 4);
            floatx4 v;
            v[0] = er[it * 4 + 0] + (float)((xw << 24) >> 24) * xsDf;
            v[1] = er[it * 4 + 1] + (float)((xw << 16) >> 24) * xsDf;
            v[2] = er[it * 4 + 2] + (float)((xw << 8) >> 24) * xsDf;
            v[3] = er[it * 4 + 3] + (float)(xw >> 24) * xsDf;
            *(floatx4*)(out + go + it * 4) = v;
        }
        __syncthreads();
    }
}

extern "C" void kernel_launch(void* const* d_in, const int* in_sizes, int n_in,
                              void* d_out, int out_size, void* d_ws, size_t ws_size,
                              hipStream_t stream)
{
    const int* xq = (const int*)d_in[0];
    const int* dt = (const int*)d_in[1];
    const int* Bm = (const int*)d_in[2];
    const int* Cm = (const int*)d_in[3];
    const int* qA = (const int*)d_in[4];
    const int* qD = (const int*)d_in[5];
    const float* dt_bias = (const float*)d_in[6];
    const float* A_scale = (const float*)d_in[7];
    const float* D_scale = (const float*)d_in[8];
    const float* dt_scale = (const float*)d_in[9];
    const float* x_scale = (const float*)d_in[10];
    const float* B_scale = (const float*)d_in[11];
    const float* C_scale = (const float*)d_in[12];
    float* out = (float*)d_out;

    char* ws = (char*)d_ws;
    float* cum          = (float*)(ws);
    float* cdecay       = (float*)(ws + 524288);
    float* CBt          = (float*)(ws + 526336);
    float* states       = (float*)(ws + 4720640);
    _Float16* xTdtT     = (_Float16*)(ws + 21497856);
    _Float16* statesHT  = (_Float16*)(ws + 38275072);
    _Float16* Bt16T     = (_Float16*)(ws + 46663680);
    _Float16* C16T      = (_Float16*)(ws + 47712256);
    signed char* x8     = (signed char*)(ws + 48760832);

    kA<<<dim3(416), dim3(256), 0, stream>>>(Bm, Cm, B_scale, C_scale, CBt, Bt16T, C16T);
    k013<<<dim3(512), dim3(256), 0, stream>>>(dt, qA, dt_bias, A_scale, dt_scale,
                                              xq, x_scale, B_scale, Bt16T,
                                              cum, cdecay, xTdtT, x8, states);
    k4_scan<<<dim3(512), dim3(256), 0, stream>>>(cdecay, states, statesHT);
    k56<<<dim3(512), dim3(256), 0, stream>>>(x8, qD, cum, CBt, xTdtT, C16T, statesHT,
                                             C_scale, x_scale, D_scale, out);
}